// Round 14
// baseline (57.685 us; speedup 1.0000x reference)
//
#include <hip/hip_runtime.h>
#include <hip/hip_fp16.h>

#define IN_DIM  16384
#define OUT_DIM 16384
#define BATCH   2048
#define TPB     512
#define ITS     (OUT_DIM / (TPB * 4))   // 8 j-iterations (4 columns each)
#define LDG     (IN_DIM / (TPB * 4))    // 8 x 16B global_load_lds per thread

typedef float f32x4 __attribute__((ext_vector_type(4)));

// Two half2's per output column: ab = (c0, c1), cd = (c2, c3). 8 bytes.
struct h2x2 { __half2 ab, cd; };

// OP_COEFFS from the reference, row-major [16][4]
__device__ __constant__ float OPC[16][4] = {
    {0.f, 0.f, 0.f, 0.f}, {0.f, 0.f, 0.f, 1.f}, {0.f, 1.f, 0.f, -1.f}, {0.f, 1.f, 0.f, 0.f},
    {0.f, 0.f, 1.f, -1.f}, {0.f, 0.f, 1.f, 0.f}, {0.f, 1.f, 1.f, -2.f}, {0.f, 1.f, 1.f, -1.f},
    {1.f, -1.f, -1.f, 1.f}, {1.f, -1.f, -1.f, 2.f}, {1.f, 0.f, -1.f, 0.f}, {1.f, 0.f, -1.f, 1.f},
    {1.f, -1.f, 0.f, 0.f}, {1.f, -1.f, 0.f, 1.f}, {1.f, 0.f, 0.f, -1.f}, {1.f, 0.f, 0.f, 0.f}};

// Prep: coef (f16x4) + packed f32-LDS byte offsets: (idx_a*4) | (idx_b*4)<<16.
__global__ __launch_bounds__(256) void prep_kernel(const float* __restrict__ w,
                                                   const int* __restrict__ ia,
                                                   const int* __restrict__ ib,
                                                   h2x2* __restrict__ coefh,
                                                   unsigned* __restrict__ packed) {
    int j = blockIdx.x * 256 + threadIdx.x;
    if (j >= OUT_DIM) return;

    const float4* wr = (const float4*)(w + (size_t)j * 16);
    float wv[16];
    float4 w0 = wr[0], w1 = wr[1], w2 = wr[2], w3 = wr[3];
    wv[0] = w0.x; wv[1] = w0.y; wv[2] = w0.z; wv[3] = w0.w;
    wv[4] = w1.x; wv[5] = w1.y; wv[6] = w1.z; wv[7] = w1.w;
    wv[8] = w2.x; wv[9] = w2.y; wv[10] = w2.z; wv[11] = w2.w;
    wv[12] = w3.x; wv[13] = w3.y; wv[14] = w3.z; wv[15] = w3.w;

    float m = wv[0];
#pragma unroll
    for (int k = 1; k < 16; ++k) m = fmaxf(m, wv[k]);
    float s = 0.f;
#pragma unroll
    for (int k = 0; k < 16; ++k) { wv[k] = expf(wv[k] - m); s += wv[k]; }
    float inv = 1.f / s;

    float c0 = 0.f, c1 = 0.f, c2 = 0.f, c3 = 0.f;
#pragma unroll
    for (int k = 0; k < 16; ++k) {
        float p = wv[k];
        c0 = fmaf(p, OPC[k][0], c0);
        c1 = fmaf(p, OPC[k][1], c1);
        c2 = fmaf(p, OPC[k][2], c2);
        c3 = fmaf(p, OPC[k][3], c3);
    }
    h2x2 c;
    c.ab = __floats2half2_rn(c0 * inv, c1 * inv);
    c.cd = __floats2half2_rn(c2 * inv, c3 * inv);
    coefh[j] = c;
    packed[j] = ((unsigned)ia[j] << 2) | ((unsigned)ib[j] << 18);
}

// Single-shot, one row per block, f32 row staged by DMA:
// 8 x global_load_lds(16B) per thread — zero VGPR round-trip, no pack VALU,
// all loads in flight at once (64 KiB/CU outstanding >> latency-BW product).
// 64 KiB LDS -> 2 blocks/CU: while this block waits on its DMA at the
// barrier, the co-resident block computes/stores — the HBM read stream and
// write stream finally overlap instead of alternating (R12/R13 diagnosis).
// Depth-1 pi/cf prefetch (R12) kept; coef f16 (absmax 0.0039, thr 0.018).
__global__ __launch_bounds__(TPB, 2) void logic_kernel(const float* __restrict__ x,
                                                       const unsigned* __restrict__ packed,
                                                       const h2x2* __restrict__ coefh,
                                                       float* __restrict__ out) {
    __shared__ float lds[IN_DIM];  // 64 KiB -> 2 blocks/CU

    const int tid = threadIdx.x;
    const size_t row = blockIdx.x;

    // Stage: pure DMA, no registers.
    {
        const float* src = x + row * IN_DIM;
#pragma unroll
        for (int k = 0; k < LDG; ++k) {
            const int off = (k * TPB + tid) * 4;  // float index, 16B granules
            __builtin_amdgcn_global_load_lds(
                (const __attribute__((address_space(1))) void*)(src + off),
                (__attribute__((address_space(3))) void*)(lds + off),
                16, 0, 0);
        }
    }

    // Prefetch iteration 0's pi/cf while the DMA flies.
    uint4 pi = *(const uint4*)(packed + tid * 4);
    h2x2 cA = coefh[tid * 4 + 0];
    h2x2 cB = coefh[tid * 4 + 1];
    h2x2 cC = coefh[tid * 4 + 2];
    h2x2 cD = coefh[tid * 4 + 3];

    // Drain LDS-DMA (and the prefetch) explicitly, then sync (R2 lesson).
    asm volatile("s_waitcnt vmcnt(0)" ::: "memory");
    __syncthreads();

    const char* bufc = (const char*)lds;
    float* outr = out + row * IN_DIM;

#pragma unroll
    for (int it = 0; it < ITS; ++it) {
        // Next iteration's pi/cf fly under this iteration's gather+FMA+store.
        uint4 pin = pi;
        h2x2 nA = cA, nB = cB, nC = cC, nD = cD;
        if (it + 1 < ITS) {
            const int jn = ((it + 1) * TPB + tid) * 4;
            pin = *(const uint4*)(packed + jn);
            nA = coefh[jn + 0];
            nB = coefh[jn + 1];
            nC = coefh[jn + 2];
            nD = coefh[jn + 3];
        }
        __builtin_amdgcn_sched_barrier(0);  // keep prefetch issue ahead of compute

        const int j0 = (it * TPB + tid) * 4;
        f32x4 o;
#define COL(P, CF, FLD)                                                             \
        {                                                                           \
            float a = *(const float*)(bufc + ((P) & 0xFFFFu));                      \
            float b = *(const float*)(bufc + ((P) >> 16));                          \
            float c0 = __low2float(CF.ab), c1 = __high2float(CF.ab);                \
            float c2 = __low2float(CF.cd), c3 = __high2float(CF.cd);                \
            o.FLD = fmaf(a, fmaf(c3, b, c1), fmaf(c2, b, c0));                      \
        }
        COL(pi.x, cA, x)
        COL(pi.y, cB, y)
        COL(pi.z, cC, z)
        COL(pi.w, cD, w)
#undef COL
        *(f32x4*)(outr + j0) = o;

        pi = pin; cA = nA; cB = nB; cC = nC; cD = nD;
    }
}

extern "C" void kernel_launch(void* const* d_in, const int* in_sizes, int n_in,
                              void* d_out, int out_size, void* d_ws, size_t ws_size,
                              hipStream_t stream) {
    const float* x = (const float*)d_in[0];
    const int* ia = (const int*)d_in[1];
    const int* ib = (const int*)d_in[2];
    const float* w = (const float*)d_in[3];
    float* out = (float*)d_out;

    // ws layout: [0, 128 KiB) coefh h2x2[OUT_DIM]; [128 KiB, 192 KiB) packed u32[OUT_DIM]
    h2x2* coefh = (h2x2*)d_ws;
    unsigned* packed = (unsigned*)((char*)d_ws + (size_t)OUT_DIM * sizeof(h2x2));

    prep_kernel<<<OUT_DIM / 256, 256, 0, stream>>>(w, ia, ib, coefh, packed);
    logic_kernel<<<BATCH, TPB, 0, stream>>>(x, packed, coefh, out);
}